// Round 6
// baseline (599.029 us; speedup 1.0000x reference)
//
#include <hip/hip_runtime.h>
#include <math.h>

#define V 16
#define NC 10
#define NPX 1024
#define NPY 1024

static constexpr float TF = 1e-4f;
static constexpr float INV_TF = 1.0f / TF;

// ws layout in 4-byte units (round-1 core + scatter lists):
enum {
    WS_SP  = 0,              // sp[16]
    WS_D   = 16,             // d[16]
    WS_OD  = 32,             // 1-d[16]
    WS_CLS = 48,             // cls[16][10]
    WS_CNL = 208,            // int cntL[16]
    WS_CNR = 224,            // int cntR[16]
    WS_CHL = 240,            // int childL[16][16]  (n*16+k)
    WS_CHR = 496,            // int childR[16][16]
    WS_VLL = 752,            // float valL[16][16]
    WS_VLR = 1008,           // float valR[16][16]
    WS_TOTAL = 1264          // ~5.1 KB
};

// Parameter numerics identical to round-1 (libm expf, true division):
// the T=1e-4 sigmoids amplify parameter ulp drift ~1e4x.
__global__ void setup_kernel(const float* __restrict__ split_points,
                             const float* __restrict__ dir_logits,
                             const float* __restrict__ class_logits,
                             const float* __restrict__ child_logits,
                             float* __restrict__ ws) {
    const int t = threadIdx.x;
    int* wsi = (int*)ws;
    if (t < V) {
        float s = fminf(fmaxf(split_points[t], 0.1f), 0.9f);
        ws[WS_SP + t] = s;
        float dd = 1.0f / (1.0f + expf(-dir_logits[t]));
        ws[WS_D + t] = dd;
        ws[WS_OD + t] = 1.0f - dd;
    }
    if (t < 2 * V) {
        // softmax(child_logits[n, side, :] / TF) -> sparse (child, val) list.
        // Keeps ALL nonzero entries, so the scatter equals the dense chain
        // exactly up to the mul-vs-fmaf rounding on non-1.0 entries.
        const int n = t & (V - 1);
        const int side = t >> 4;             // 0 = left, 1 = right
        const float* row = child_logits + n * 2 * V + side * V;
        float u[V]; float m = -INFINITY;
        #pragma unroll
        for (int c = 0; c < V; ++c) { u[c] = row[c] * INV_TF; m = fmaxf(m, u[c]); }
        float sum = 0.0f;
        #pragma unroll
        for (int c = 0; c < V; ++c) { u[c] = expf(u[c] - m); sum += u[c]; }
        int cnt = 0;
        const int ch_at = (side ? WS_CHR : WS_CHL) + n * 16;
        const int vl_at = (side ? WS_VLR : WS_VLL) + n * 16;
        #pragma unroll
        for (int c = 0; c < V; ++c) {
            float p = u[c] / sum;            // true division, as round-1
            if (p != 0.0f) {
                wsi[ch_at + cnt] = c;
                ws[vl_at + cnt] = p;
                ++cnt;
            }
        }
        wsi[(side ? WS_CNR : WS_CNL) + n] = cnt;
        // pad slot 0 is always valid (cnt >= 1: softmax max entry ~1.0)
    } else if (t < 3 * V) {
        const int n = t - 2 * V;
        float u[NC]; float m = -INFINITY;
        #pragma unroll
        for (int c = 0; c < NC; ++c) { u[c] = class_logits[n * NC + c] * INV_TF; m = fmaxf(m, u[c]); }
        float sum = 0.0f;
        #pragma unroll
        for (int c = 0; c < NC; ++c) { u[c] = expf(u[c] - m); sum += u[c]; }
        #pragma unroll
        for (int c = 0; c < NC; ++c) ws[WS_CLS + n * NC + c] = u[c] / sum;
    }
}

__device__ __forceinline__ float fast_sigmoid(float z) {
    // identical to round-1 (passing): saturates to exact 0.0 / 1.0
    return __builtin_amdgcn_rcpf(1.0f + __expf(-z));
}

#define SLOT_STRIDE 66   // floats; 2-lane/bank aliasing only (free)

__global__ __launch_bounds__(256) void fractal_kernel(
        const float* __restrict__ ws,
        const float* __restrict__ xs,
        const float* __restrict__ ys,
        const int* __restrict__ max_depth_p,
        float* __restrict__ out,
        int B) {
    __shared__ float lds[4 * V * SLOT_STRIDE];    // 16.5 KB/block
    const int lane = threadIdx.x & 63;
    const int wave = threadIdx.x >> 6;
    float* A = lds + wave * (V * SLOT_STRIDE);    // per-wave private

    const int tile = blockIdx.x * 4 + wave;       // one wave = one 8x8 tile
    if (tile >= (B >> 6)) return;
    const int tx = tile >> 7;                     // 128 tiles per dim
    const int ty = tile & 127;
    const int ix = tx * 8 + (lane >> 3);
    const int iy = ty * 8 + (lane & 7);
    const int p = ix * NPY + iy;

    const float x = xs[p];
    const float y = ys[p];
    const int depth = *max_depth_p;
    const int* wsi = (const int*)ws;

    // zero accumulator slots (re-zeroed after each depth's readback)
    #pragma unroll
    for (int c = 0; c < V; ++c) A[c * SLOT_STRIDE + lane] = 0.0f;

    // precompute k=0 scatter addresses (loop-invariant; 32 VGPRs)
    int idxL0[V], idxR0[V];
    #pragma unroll
    for (int n = 0; n < V; ++n) {
        idxL0[n] = wsi[WS_CHL + n * 16] * SLOT_STRIDE + lane;
        idxR0[n] = wsi[WS_CHR + n * 16] * SLOT_STRIDE + lane;
    }

    float np[V];
    #pragma unroll
    for (int n = 0; n < V; ++n) np[n] = 0.0f;
    np[0] = 1.0f;
    float minx = 0.0f, maxx = 1.0f, miny = 0.0f, maxy = 1.0f;

    #pragma unroll 1
    for (int t = 0; t < depth; ++t) {
        const float rx = maxx - minx;
        const float ry = maxy - miny;
        float sum_l = 0.0f, sum_r = 0.0f;
        float acc_lmaxx = 0.0f, acc_rminx = 0.0f;
        float acc_lmaxy = 0.0f, acc_rminy = 0.0f;

        #pragma unroll
        for (int n = 0; n < V; ++n) {
            // zero-prob nodes contribute exact zeros -> skip is bit-exact
            if (__any(np[n] != 0.0f)) {
                const float spn = ws[WS_SP + n];   // uniform -> s_load
                const float dn  = ws[WS_D + n];
                const float odn = ws[WS_OD + n];
                const float sx = fmaf(spn, rx, minx);
                const float sy = fmaf(spn, ry, miny);
                const float h = fast_sigmoid((sx - x) * INV_TF);
                const float v = fast_sigmoid((sy - y) * INV_TF);
                const float l = fmaf(dn, v, odn * h) * np[n];
                const float r = np[n] - l;
                sum_l += l;
                sum_r += r;
                acc_lmaxx = fmaf(fmaf(dn, maxx, odn * sx), l, acc_lmaxx);
                acc_rminx = fmaf(fmaf(dn, minx, odn * sx), r, acc_rminx);
                acc_lmaxy = fmaf(fmaf(odn, maxy, dn * sy), l, acc_lmaxy);
                acc_rminy = fmaf(fmaf(odn, miny, dn * sy), r, acc_rminy);
                // scatter via LDS float-atomics (ds_add_f32, no return).
                // Per-child order matches the dense fmaf chain: n ascending,
                // r before l. val==1.0 entries are bit-exact (mul is exact,
                // single add-rounding == fmaf with coeff 1.0).
                atomicAdd(&A[idxR0[n]], r * ws[WS_VLR + n * 16]);
                const int cnr = wsi[WS_CNR + n];   // uniform
                if (cnr > 1) {
                    for (int k = 1; k < cnr; ++k)
                        atomicAdd(&A[wsi[WS_CHR + n * 16 + k] * SLOT_STRIDE + lane],
                                  r * ws[WS_VLR + n * 16 + k]);
                }
                atomicAdd(&A[idxL0[n]], l * ws[WS_VLL + n * 16]);
                const int cnl = wsi[WS_CNL + n];   // uniform
                if (cnl > 1) {
                    for (int k = 1; k < cnl; ++k)
                        atomicAdd(&A[wsi[WS_CHL + n * 16 + k] * SLOT_STRIDE + lane],
                                  l * ws[WS_VLL + n * 16 + k]);
                }
            }
        }

        // same-wave LDS ops are in-order; barrier only fences the compiler
        asm volatile("" ::: "memory");
        float nxt[V];
        #pragma unroll
        for (int c = 0; c < V; ++c) nxt[c] = A[c * SLOT_STRIDE + lane];
        #pragma unroll
        for (int c = 0; c < V; ++c) A[c * SLOT_STRIDE + lane] = 0.0f;
        asm volatile("" ::: "memory");

        float wsum = fmaxf(sum_l + sum_r, 1e-10f);
        const float inv_w = __builtin_amdgcn_rcpf(wsum);
        float psum = 0.0f;
        #pragma unroll
        for (int c = 0; c < V; ++c) psum += nxt[c];
        const float inv_p = __builtin_amdgcn_rcpf(fmaxf(psum, 1e-10f));
        #pragma unroll
        for (int c = 0; c < V; ++c) np[c] = nxt[c] * inv_p;

        const float nminx = fmaf(minx, sum_l, acc_rminx) * inv_w;
        const float nmaxx = fmaf(maxx, sum_r, acc_lmaxx) * inv_w;
        const float nminy = fmaf(miny, sum_l, acc_rminy) * inv_w;
        const float nmaxy = fmaf(maxy, sum_r, acc_lmaxy) * inv_w;
        minx = nminx; maxx = nmaxx; miny = nminy; maxy = nmaxy;
    }

    // class_probs = np @ cls (dense, verbatim round-1)
    float o[NC];
    #pragma unroll
    for (int c = 0; c < NC; ++c) o[c] = 0.0f;
    #pragma unroll
    for (int n = 0; n < V; ++n) {
        if (__any(np[n] != 0.0f)) {
            #pragma unroll
            for (int c = 0; c < NC; ++c) o[c] = fmaf(np[n], ws[WS_CLS + n * NC + c], o[c]);
        }
    }

    float2* op = reinterpret_cast<float2*>(out + (size_t)p * NC);
    #pragma unroll
    for (int c = 0; c < NC / 2; ++c) op[c] = make_float2(o[2 * c], o[2 * c + 1]);
}

extern "C" void kernel_launch(void* const* d_in, const int* in_sizes, int n_in,
                              void* d_out, int out_size, void* d_ws, size_t ws_size,
                              hipStream_t stream) {
    const float* split_points = (const float*)d_in[0];
    const float* dir_logits   = (const float*)d_in[1];
    const float* class_logits = (const float*)d_in[2];
    const float* child_logits = (const float*)d_in[3];
    const float* xs           = (const float*)d_in[4];
    const float* ys           = (const float*)d_in[5];
    const int*   max_depth    = (const int*)d_in[6];
    float* out = (float*)d_out;
    float* ws  = (float*)d_ws;   // needs WS_TOTAL*4 ~ 5.1 KB

    hipLaunchKernelGGL(setup_kernel, dim3(1), dim3(64), 0, stream,
                       split_points, dir_logits, class_logits, child_logits, ws);

    const int B = in_sizes[4];                 // 1048576 points
    const int blocks = (B + 255) / 256;        // 4 waves/block, 1 tile/wave
    hipLaunchKernelGGL(fractal_kernel, dim3(blocks), dim3(256), 0, stream,
                       ws, xs, ys, max_depth, out, B);
}